// Round 1
// baseline (1975.887 us; speedup 1.0000x reference)
//
#include <hip/hip_runtime.h>
#include <hip/hip_bf16.h>
#include <cstdint>
#include <cstddef>

#define HID 128

// ============================ CSR build ============================

__global__ void k_count(const int* __restrict__ dst, int E, int* __restrict__ deg) {
    int e = blockIdx.x * blockDim.x + threadIdx.x;
    if (e < E) atomicAdd(&deg[dst[e]], 1);
}

// 1024 elements per block (256 thr x 4). Exclusive prefix within block -> rowptr,
// block totals -> partials.
__global__ void k_scan1(const int* __restrict__ deg, int* __restrict__ rowptr,
                        int* __restrict__ partials, int n) {
    __shared__ int s[256];
    int t = threadIdx.x;
    int base = blockIdx.x * 1024 + t * 4;
    int v0 = 0, v1 = 0, v2 = 0, v3 = 0;
    if (base + 0 < n) v0 = deg[base + 0];
    if (base + 1 < n) v1 = deg[base + 1];
    if (base + 2 < n) v2 = deg[base + 2];
    if (base + 3 < n) v3 = deg[base + 3];
    s[t] = v0 + v1 + v2 + v3;
    __syncthreads();
    #pragma unroll
    for (int off = 1; off < 256; off <<= 1) {
        int add = (t >= off) ? s[t - off] : 0;
        __syncthreads();
        s[t] += add;
        __syncthreads();
    }
    if (t == 255) partials[blockIdx.x] = s[255];
    int run = (t == 0) ? 0 : s[t - 1];
    if (base + 0 < n) rowptr[base + 0] = run; run += v0;
    if (base + 1 < n) rowptr[base + 1] = run; run += v1;
    if (base + 2 < n) rowptr[base + 2] = run; run += v2;
    if (base + 3 < n) rowptr[base + 3] = run;
}

// exclusive scan of block partials (nb <= 128)
__global__ void k_scan2(int* __restrict__ partials, int nb) {
    __shared__ int s[128];
    int t = threadIdx.x;
    s[t] = (t < nb) ? partials[t] : 0;
    __syncthreads();
    #pragma unroll
    for (int off = 1; off < 128; off <<= 1) {
        int add = (t >= off) ? s[t - off] : 0;
        __syncthreads();
        s[t] += add;
        __syncthreads();
    }
    int excl = (t == 0) ? 0 : s[t - 1];
    if (t < nb) partials[t] = excl;
}

__global__ void k_scan3(int* __restrict__ rowptr, const int* __restrict__ partials,
                        int n, int E) {
    int i = blockIdx.x * blockDim.x + threadIdx.x;
    if (i < n) rowptr[i] += partials[i >> 10];
    if (i == n) rowptr[n] = E;
}

__global__ void k_fill(const int* __restrict__ src, const int* __restrict__ dst, int E,
                       const int* __restrict__ rowptr, int* __restrict__ fillc,
                       int* __restrict__ csr) {
    int e = blockIdx.x * blockDim.x + threadIdx.x;
    if (e < E) {
        int d = dst[e];
        int p = atomicAdd(&fillc[d], 1);
        csr[rowptr[d] + p] = src[e];
    }
}

// ============================ mean aggregation ============================
// one block (128 threads) per destination node; thread = feature channel
__global__ void k_agg(const float* __restrict__ x, const int* __restrict__ rowptr,
                      const int* __restrict__ csr, float* __restrict__ mean) {
    int i = blockIdx.x;
    int ch = threadIdx.x;
    int b = rowptr[i], e = rowptr[i + 1];
    float a0 = 0.f, a1 = 0.f, a2 = 0.f, a3 = 0.f;
    int j = b;
    for (; j + 3 < e; j += 4) {
        int s0 = csr[j], s1 = csr[j + 1], s2 = csr[j + 2], s3 = csr[j + 3];
        a0 += x[(size_t)s0 * HID + ch];
        a1 += x[(size_t)s1 * HID + ch];
        a2 += x[(size_t)s2 * HID + ch];
        a3 += x[(size_t)s3 * HID + ch];
    }
    for (; j < e; ++j) a0 += x[(size_t)csr[j] * HID + ch];
    float acc = (a0 + a1) + (a2 + a3);
    float d = (float)(e - b);
    mean[(size_t)i * HID + ch] = acc / fmaxf(d, 1.0f);
}

// ============================ layer GEMM ============================
// out[i,:] = relu( mean[i,:] @ Wl + x[i,:] @ Wr + bl )   (M x 256 x 128)
// tile: 128 rows x 128 cols, K staged 32 at a time; 256 thr, 8x8 micro-tile
__global__ __launch_bounds__(256) void k_gemm_layer(
    const float* __restrict__ mean, const float* __restrict__ x,
    const float* __restrict__ Wl, const float* __restrict__ Wr,
    const float* __restrict__ bl, float* __restrict__ out, int M)
{
    __shared__ float As[32][132];   // transposed: As[k][row]
    __shared__ float Bs[32][128];
    int tid = threadIdx.x;
    int i0 = blockIdx.x * 128;
    int rg = tid & 15, cg = tid >> 4;
    float acc[8][8];
    #pragma unroll
    for (int u = 0; u < 8; u++)
        #pragma unroll
        for (int v = 0; v < 8; v++) acc[u][v] = 0.f;

    int lr = tid >> 1;            // row 0..127
    int lh = (tid & 1) * 16;      // k-halves 0..15 / 16..31

    for (int kt = 0; kt < 8; ++kt) {
        const float* Asrc = (kt < 4) ? mean : x;
        const float* Bsrc = (kt < 4) ? Wl : Wr;
        int kbase = (kt & 3) * 32;
        int grow = i0 + lr;
        float4 av[4];
        if (grow < M) {
            const float4* p = (const float4*)(Asrc + (size_t)grow * HID + kbase + lh);
            av[0] = p[0]; av[1] = p[1]; av[2] = p[2]; av[3] = p[3];
        } else {
            av[0] = av[1] = av[2] = av[3] = make_float4(0.f, 0.f, 0.f, 0.f);
        }
        float4 bv[4];
        #pragma unroll
        for (int p2 = 0; p2 < 4; p2++) {
            int q = tid + 256 * p2;
            int kb = q >> 5, col = (q & 31) * 4;
            bv[p2] = *(const float4*)(Bsrc + (size_t)(kbase + kb) * HID + col);
        }
        __syncthreads();
        const float* avf = (const float*)av;
        #pragma unroll
        for (int jj = 0; jj < 16; jj++) As[lh + jj][lr] = avf[jj];
        #pragma unroll
        for (int p2 = 0; p2 < 4; p2++) {
            int q = tid + 256 * p2;
            int kb = q >> 5, col = (q & 31) * 4;
            *(float4*)&Bs[kb][col] = bv[p2];
        }
        __syncthreads();
        #pragma unroll
        for (int kk = 0; kk < 32; kk++) {
            float4 A0 = *(const float4*)&As[kk][rg * 8];
            float4 A1 = *(const float4*)&As[kk][rg * 8 + 4];
            float4 B0 = *(const float4*)&Bs[kk][cg * 8];
            float4 B1 = *(const float4*)&Bs[kk][cg * 8 + 4];
            float a[8] = {A0.x, A0.y, A0.z, A0.w, A1.x, A1.y, A1.z, A1.w};
            float b[8] = {B0.x, B0.y, B0.z, B0.w, B1.x, B1.y, B1.z, B1.w};
            #pragma unroll
            for (int u = 0; u < 8; u++)
                #pragma unroll
                for (int v = 0; v < 8; v++) acc[u][v] = fmaf(a[u], b[v], acc[u][v]);
        }
    }
    float4 bb0 = *(const float4*)(bl + cg * 8);
    float4 bb1 = *(const float4*)(bl + cg * 8 + 4);
    float bias[8] = {bb0.x, bb0.y, bb0.z, bb0.w, bb1.x, bb1.y, bb1.z, bb1.w};
    #pragma unroll
    for (int u = 0; u < 8; u++) {
        int grow = i0 + rg * 8 + u;
        if (grow < M) {
            float4 o0, o1;
            o0.x = fmaxf(acc[u][0] + bias[0], 0.f);
            o0.y = fmaxf(acc[u][1] + bias[1], 0.f);
            o0.z = fmaxf(acc[u][2] + bias[2], 0.f);
            o0.w = fmaxf(acc[u][3] + bias[3], 0.f);
            o1.x = fmaxf(acc[u][4] + bias[4], 0.f);
            o1.y = fmaxf(acc[u][5] + bias[5], 0.f);
            o1.z = fmaxf(acc[u][6] + bias[6], 0.f);
            o1.w = fmaxf(acc[u][7] + bias[7], 0.f);
            float* op = out + (size_t)grow * HID + cg * 8;
            *(float4*)op = o0;
            *(float4*)(op + 4) = o1;
        }
    }
}

// ============================ fused edge MLP ============================
// logits[e,:] = relu([x[qs[e]],x[qd[e]]] @ W1 + b1) @ W2 + b2
union MlpSmem {
    struct { float As[32][132]; float Bs[32][128]; } s1;
    struct { float Hs[128][132]; float W2s[128 * 8]; } s2;
};

__global__ __launch_bounds__(256) void k_mlp(
    const float* __restrict__ x, const int* __restrict__ qs, const int* __restrict__ qd,
    const float* __restrict__ W1, const float* __restrict__ b1,
    const float* __restrict__ W2, const float* __restrict__ b2,
    float* __restrict__ out, int Eq)
{
    __shared__ MlpSmem sm;
    int tid = threadIdx.x;
    int e0 = blockIdx.x * 128;
    int rg = tid & 15, cg = tid >> 4;
    float acc[8][8];
    #pragma unroll
    for (int u = 0; u < 8; u++)
        #pragma unroll
        for (int v = 0; v < 8; v++) acc[u][v] = 0.f;

    int lr = tid >> 1;
    int lh = (tid & 1) * 16;
    int erow = e0 + lr;
    int ecl = (erow < Eq) ? erow : 0;
    int nodeS = qs[ecl], nodeD = qd[ecl];

    for (int kt = 0; kt < 8; ++kt) {
        int node = (kt < 4) ? nodeS : nodeD;
        int kbase = (kt & 3) * 32;
        const float4* p = (const float4*)(x + (size_t)node * HID + kbase + lh);
        float4 av[4] = {p[0], p[1], p[2], p[3]};
        float4 bv[4];
        #pragma unroll
        for (int p2 = 0; p2 < 4; p2++) {
            int q = tid + 256 * p2;
            int kb = q >> 5, col = (q & 31) * 4;
            bv[p2] = *(const float4*)(W1 + (size_t)(kt * 32 + kb) * HID + col);
        }
        __syncthreads();
        const float* avf = (const float*)av;
        #pragma unroll
        for (int jj = 0; jj < 16; jj++) sm.s1.As[lh + jj][lr] = avf[jj];
        #pragma unroll
        for (int p2 = 0; p2 < 4; p2++) {
            int q = tid + 256 * p2;
            int kb = q >> 5, col = (q & 31) * 4;
            *(float4*)&sm.s1.Bs[kb][col] = bv[p2];
        }
        __syncthreads();
        #pragma unroll
        for (int kk = 0; kk < 32; kk++) {
            float4 A0 = *(const float4*)&sm.s1.As[kk][rg * 8];
            float4 A1 = *(const float4*)&sm.s1.As[kk][rg * 8 + 4];
            float4 B0 = *(const float4*)&sm.s1.Bs[kk][cg * 8];
            float4 B1 = *(const float4*)&sm.s1.Bs[kk][cg * 8 + 4];
            float a[8] = {A0.x, A0.y, A0.z, A0.w, A1.x, A1.y, A1.z, A1.w};
            float b[8] = {B0.x, B0.y, B0.z, B0.w, B1.x, B1.y, B1.z, B1.w};
            #pragma unroll
            for (int u = 0; u < 8; u++)
                #pragma unroll
                for (int v = 0; v < 8; v++) acc[u][v] = fmaf(a[u], b[v], acc[u][v]);
        }
    }

    // h = relu(acc + b1) -> LDS (reuse union)
    float4 b1v0 = *(const float4*)(b1 + cg * 8);
    float4 b1v1 = *(const float4*)(b1 + cg * 8 + 4);
    float bias[8] = {b1v0.x, b1v0.y, b1v0.z, b1v0.w, b1v1.x, b1v1.y, b1v1.z, b1v1.w};
    __syncthreads();   // all stage-1 LDS reads done before union reuse
    #pragma unroll
    for (int u = 0; u < 8; u++) {
        float4 h0, h1;
        h0.x = fmaxf(acc[u][0] + bias[0], 0.f);
        h0.y = fmaxf(acc[u][1] + bias[1], 0.f);
        h0.z = fmaxf(acc[u][2] + bias[2], 0.f);
        h0.w = fmaxf(acc[u][3] + bias[3], 0.f);
        h1.x = fmaxf(acc[u][4] + bias[4], 0.f);
        h1.y = fmaxf(acc[u][5] + bias[5], 0.f);
        h1.z = fmaxf(acc[u][6] + bias[6], 0.f);
        h1.w = fmaxf(acc[u][7] + bias[7], 0.f);
        *(float4*)&sm.s2.Hs[rg * 8 + u][cg * 8] = h0;
        *(float4*)&sm.s2.Hs[rg * 8 + u][cg * 8 + 4] = h1;
    }
    *(float4*)&sm.s2.W2s[tid * 4] = *(const float4*)(W2 + tid * 4);
    __syncthreads();

    // logits: thread -> (edge e = tid/2, 4 classes)
    int e = tid >> 1;
    int cp = (tid & 1) * 4;
    float4 o;
    o.x = b2[cp + 0]; o.y = b2[cp + 1]; o.z = b2[cp + 2]; o.w = b2[cp + 3];
    #pragma unroll
    for (int k4 = 0; k4 < 32; k4++) {
        float4 hv = *(const float4*)&sm.s2.Hs[e][k4 * 4];
        float4 w0 = *(const float4*)&sm.s2.W2s[(k4 * 4 + 0) * 8 + cp];
        float4 w1 = *(const float4*)&sm.s2.W2s[(k4 * 4 + 1) * 8 + cp];
        float4 w2 = *(const float4*)&sm.s2.W2s[(k4 * 4 + 2) * 8 + cp];
        float4 w3 = *(const float4*)&sm.s2.W2s[(k4 * 4 + 3) * 8 + cp];
        o.x += hv.x * w0.x + hv.y * w1.x + hv.z * w2.x + hv.w * w3.x;
        o.y += hv.x * w0.y + hv.y * w1.y + hv.z * w2.y + hv.w * w3.y;
        o.z += hv.x * w0.z + hv.y * w1.z + hv.z * w2.z + hv.w * w3.z;
        o.w += hv.x * w0.w + hv.y * w1.w + hv.z * w2.w + hv.w * w3.w;
    }
    int eg = e0 + e;
    if (eg < Eq) *(float4*)(out + (size_t)eg * 8 + cp) = o;
}

// ============================ launch ============================

extern "C" void kernel_launch(void* const* d_in, const int* in_sizes, int n_in,
                              void* d_out, int out_size, void* d_ws, size_t ws_size,
                              hipStream_t stream) {
    const float* node_emb = (const float*)d_in[0];
    const float* Wl0 = (const float*)d_in[1];
    const float* bl0 = (const float*)d_in[2];
    const float* Wr0 = (const float*)d_in[3];
    const float* Wl1 = (const float*)d_in[4];
    const float* bl1 = (const float*)d_in[5];
    const float* Wr1 = (const float*)d_in[6];
    const float* W1  = (const float*)d_in[7];
    const float* b1  = (const float*)d_in[8];
    const float* W2  = (const float*)d_in[9];
    const float* b2  = (const float*)d_in[10];
    const int* eidx  = (const int*)d_in[11];
    const int* eq    = (const int*)d_in[12];

    int N  = in_sizes[0] / HID;
    int E  = in_sizes[11] / 2;
    int Eq = in_sizes[12] / 2;
    const int* srcp = eidx;
    const int* dstp = eidx + E;
    const int* qs = eq;
    const int* qd = eq + Eq;
    float* outp = (float*)d_out;

    char* ws = (char*)d_ws;
    size_t off = 0;
    auto take = [&](size_t bytes) -> char* {
        char* p = ws + off;
        off += (bytes + 255) & ~(size_t)255;
        return p;
    };
    int* deg      = (int*)take((size_t)N * 4);
    int* fillc    = (int*)take((size_t)N * 4);
    int* rowptr   = (int*)take((size_t)(N + 1) * 4);
    int* partials = (int*)take(512);
    int* csr      = (int*)take((size_t)E * 4);
    float* meanb  = (float*)take((size_t)N * HID * 4);
    float* xa     = (float*)take((size_t)N * HID * 4);
    float* xb     = (float*)take((size_t)N * HID * 4);

    hipMemsetAsync(deg, 0, (size_t)N * 4, stream);
    hipMemsetAsync(fillc, 0, (size_t)N * 4, stream);

    const int TB = 256;
    int ebl = (E + TB - 1) / TB;
    k_count<<<ebl, TB, 0, stream>>>(dstp, E, deg);
    int nb = (N + 1023) / 1024;
    k_scan1<<<nb, 256, 0, stream>>>(deg, rowptr, partials, N);
    k_scan2<<<1, 128, 0, stream>>>(partials, nb);
    k_scan3<<<(N + 1 + TB - 1) / TB, TB, 0, stream>>>(rowptr, partials, N, E);
    k_fill<<<ebl, TB, 0, stream>>>(srcp, dstp, E, rowptr, fillc, csr);

    int mg = (N + 127) / 128;
    k_agg<<<N, HID, 0, stream>>>(node_emb, rowptr, csr, meanb);
    k_gemm_layer<<<mg, 256, 0, stream>>>(meanb, node_emb, Wl0, Wr0, bl0, xa, N);
    k_agg<<<N, HID, 0, stream>>>(xa, rowptr, csr, meanb);
    k_gemm_layer<<<mg, 256, 0, stream>>>(meanb, xa, Wl1, Wr1, bl1, xb, N);

    int eg = (Eq + 127) / 128;
    k_mlp<<<eg, 256, 0, stream>>>(xb, qs, qd, W1, b1, W2, b2, outp, Eq);
}

// Round 2
// 585.372 us; speedup vs baseline: 3.3754x; 3.3754x over previous
//
#include <hip/hip_runtime.h>
#include <hip/hip_bf16.h>
#include <cstdint>
#include <cstddef>

#define HID 128

typedef __attribute__((ext_vector_type(8))) __bf16 bf16x8;
typedef __attribute__((ext_vector_type(4))) float floatx4;

__device__ __forceinline__ ushort f2bf(float f) {
    uint u = __float_as_uint(f);
    u += 0x7fff + ((u >> 16) & 1);          // round-to-nearest-even
    return (ushort)(u >> 16);
}
__device__ __forceinline__ float bf2f(uint h) { return __uint_as_float(h << 16); }

// async global->LDS, 16B per lane; LDS dest must be wave-uniform base + lane*16
__device__ __forceinline__ void async16(const ushort* g, ushort* l) {
    __builtin_amdgcn_global_load_lds(
        (const __attribute__((address_space(1))) uint*)g,
        (__attribute__((address_space(3))) uint*)l, 16, 0, 0);
}

// ============================ CSR build ============================

__global__ void k_count(const int* __restrict__ dst, int E, int* __restrict__ deg) {
    int e = blockIdx.x * blockDim.x + threadIdx.x;
    if (e < E) atomicAdd(&deg[dst[e]], 1);
}

__global__ void k_scan1(const int* __restrict__ deg, int* __restrict__ rowptr,
                        int* __restrict__ partials, int n) {
    __shared__ int s[256];
    int t = threadIdx.x;
    int base = blockIdx.x * 1024 + t * 4;
    int v0 = 0, v1 = 0, v2 = 0, v3 = 0;
    if (base + 0 < n) v0 = deg[base + 0];
    if (base + 1 < n) v1 = deg[base + 1];
    if (base + 2 < n) v2 = deg[base + 2];
    if (base + 3 < n) v3 = deg[base + 3];
    s[t] = v0 + v1 + v2 + v3;
    __syncthreads();
    #pragma unroll
    for (int off = 1; off < 256; off <<= 1) {
        int add = (t >= off) ? s[t - off] : 0;
        __syncthreads();
        s[t] += add;
        __syncthreads();
    }
    if (t == 255) partials[blockIdx.x] = s[255];
    int run = (t == 0) ? 0 : s[t - 1];
    if (base + 0 < n) rowptr[base + 0] = run; run += v0;
    if (base + 1 < n) rowptr[base + 1] = run; run += v1;
    if (base + 2 < n) rowptr[base + 2] = run; run += v2;
    if (base + 3 < n) rowptr[base + 3] = run;
}

__global__ void k_scan2(int* __restrict__ partials, int nb) {
    __shared__ int s[128];
    int t = threadIdx.x;
    s[t] = (t < nb) ? partials[t] : 0;
    __syncthreads();
    #pragma unroll
    for (int off = 1; off < 128; off <<= 1) {
        int add = (t >= off) ? s[t - off] : 0;
        __syncthreads();
        s[t] += add;
        __syncthreads();
    }
    int excl = (t == 0) ? 0 : s[t - 1];
    if (t < nb) partials[t] = excl;
}

__global__ void k_scan3(int* __restrict__ rowptr, const int* __restrict__ partials,
                        int n, int E) {
    int i = blockIdx.x * blockDim.x + threadIdx.x;
    if (i < n) rowptr[i] += partials[i >> 10];
    if (i == n) rowptr[n] = E;
}

__global__ void k_fill(const int* __restrict__ src, const int* __restrict__ dst, int E,
                       const int* __restrict__ rowptr, int* __restrict__ fillc,
                       int* __restrict__ csr) {
    int e = blockIdx.x * blockDim.x + threadIdx.x;
    if (e < E) {
        int d = dst[e];
        int p = atomicAdd(&fillc[d], 1);
        csr[rowptr[d] + p] = src[e];
    }
}

// ============================ prep: fp32 -> bf16, weight transposes ============

__global__ void k_cvt(const float* __restrict__ in, ushort* __restrict__ out, int n4) {
    int i = blockIdx.x * blockDim.x + threadIdx.x;
    if (i < n4) {
        float4 v = ((const float4*)in)[i];
        ushort4 o;
        o.x = f2bf(v.x); o.y = f2bf(v.y); o.z = f2bf(v.z); o.w = f2bf(v.w);
        ((ushort4*)out)[i] = o;
    }
}

// WlrT[n][k] = (k<128 ? Wl[k][n] : Wr[k-128][n]); W1T[n][k]=W1[k][n]; W2T[n<8][k]=W2[k][n]
__global__ void k_prepw(const float* __restrict__ Wl0, const float* __restrict__ Wr0,
                        const float* __restrict__ Wl1, const float* __restrict__ Wr1,
                        const float* __restrict__ W1,  const float* __restrict__ W2,
                        ushort* __restrict__ WlrT0, ushort* __restrict__ WlrT1,
                        ushort* __restrict__ W1T,   ushort* __restrict__ W2T) {
    int idx = blockIdx.x * 256 + threadIdx.x;
    if (idx < 32768) {
        int n = idx >> 8, k = idx & 255;
        float v = (k < 128) ? Wl0[k * 128 + n] : Wr0[(k - 128) * 128 + n];
        WlrT0[n * 256 + k] = f2bf(v);
    } else if (idx < 65536) {
        int t = idx - 32768; int n = t >> 8, k = t & 255;
        float v = (k < 128) ? Wl1[k * 128 + n] : Wr1[(k - 128) * 128 + n];
        WlrT1[n * 256 + k] = f2bf(v);
    } else if (idx < 98304) {
        int t = idx - 65536; int n = t >> 8, k = t & 255;
        W1T[n * 256 + k] = f2bf(W1[k * 128 + n]);
    } else if (idx < 100352) {
        int t = idx - 98304; int n = t >> 7, k = t & 127;
        W2T[n * 128 + k] = (n < 8) ? f2bf(W2[k * 8 + n]) : (ushort)0;
    }
}

// ============================ mean aggregation (bf16 in/out) ============================
// one wave per node; lane handles 2 channels via one uint (2x bf16) load
__global__ __launch_bounds__(256) void k_agg16(const ushort* __restrict__ x,
                                               const int* __restrict__ rowptr,
                                               const int* __restrict__ csr,
                                               ushort* __restrict__ mean, int N) {
    int node = blockIdx.x * 4 + (threadIdx.x >> 6);
    int l = threadIdx.x & 63;
    if (node >= N) return;
    int b = rowptr[node], e = rowptr[node + 1];
    const uint* xv = (const uint*)x;
    float a0 = 0.f, a1 = 0.f;
    int j = b;
    for (; j + 1 < e; j += 2) {
        int s0 = csr[j], s1 = csr[j + 1];
        uint v0 = xv[(size_t)s0 * 64 + l];
        uint v1 = xv[(size_t)s1 * 64 + l];
        a0 += bf2f(v0 & 0xffffu) + bf2f(v1 & 0xffffu);
        a1 += bf2f(v0 >> 16) + bf2f(v1 >> 16);
    }
    if (j < e) {
        uint v = xv[(size_t)csr[j] * 64 + l];
        a0 += bf2f(v & 0xffffu);
        a1 += bf2f(v >> 16);
    }
    float inv = 1.f / fmaxf((float)(e - b), 1.f);
    a0 *= inv; a1 *= inv;
    ((uint*)mean)[(size_t)node * 64 + l] = (uint)f2bf(a0) | ((uint)f2bf(a1) << 16);
}

// ============================ layer GEMM (bf16 MFMA) ============================
// out[i,:] = relu([mean_i | x_i] @ [Wl;Wr] + b)  -> bf16
// block: 128 rows x 128 cols, K=256 in 8 steps of 32. 4 waves; wave w -> rows w*32..+31.
__global__ __launch_bounds__(256) void k_gemm16(
    const ushort* __restrict__ Alo, const ushort* __restrict__ Ahi,
    const ushort* __restrict__ WT, const float* __restrict__ bias,
    ushort* __restrict__ out, int M) {
    __shared__ ushort As[4096];   // [128 rows][32 k]
    __shared__ ushort Bs[4096];   // [128 n][32 k]
    int tid = threadIdx.x;
    int l = tid & 63, w = tid >> 6;
    int i0 = blockIdx.x * 128;
    int c0 = w * 64 + l, c1 = c0 + 256;
    int rA0 = c0 >> 2, sA0 = (c0 & 3) * 8;
    int rA1 = c1 >> 2, sA1 = (c1 & 3) * 8;
    int g0 = i0 + rA0; if (g0 >= M) g0 = M - 1;
    int g1 = i0 + rA1; if (g1 >= M) g1 = M - 1;
    int lm = l & 15, lq = l >> 4;

    floatx4 acc[2][8];
    #pragma unroll
    for (int rt = 0; rt < 2; rt++)
        #pragma unroll
        for (int ct = 0; ct < 8; ct++) acc[rt][ct] = (floatx4){0.f, 0.f, 0.f, 0.f};

    for (int kt = 0; kt < 8; ++kt) {
        const ushort* Asrc = (kt < 4) ? Alo : Ahi;
        int kb = (kt & 3) * 32;
        async16(Asrc + (size_t)g0 * 128 + kb + sA0, As + w * 512);
        async16(Asrc + (size_t)g1 * 128 + kb + sA1, As + 2048 + w * 512);
        async16(WT + rA0 * 256 + kt * 32 + sA0, Bs + w * 512);
        async16(WT + rA1 * 256 + kt * 32 + sA1, Bs + 2048 + w * 512);
        __syncthreads();
        bf16x8 a0 = *(const bf16x8*)(As + (w * 32 + lm) * 32 + lq * 8);
        bf16x8 a1 = *(const bf16x8*)(As + (w * 32 + 16 + lm) * 32 + lq * 8);
        #pragma unroll
        for (int ct = 0; ct < 8; ++ct) {
            bf16x8 b = *(const bf16x8*)(Bs + (ct * 16 + lm) * 32 + lq * 8);
            acc[0][ct] = __builtin_amdgcn_mfma_f32_16x16x32_bf16(a0, b, acc[0][ct], 0, 0, 0);
            acc[1][ct] = __builtin_amdgcn_mfma_f32_16x16x32_bf16(a1, b, acc[1][ct], 0, 0, 0);
        }
        __syncthreads();
    }

    float bv[8];
    #pragma unroll
    for (int ct = 0; ct < 8; ++ct) bv[ct] = bias[ct * 16 + lm];
    #pragma unroll
    for (int rt = 0; rt < 2; ++rt)
        #pragma unroll
        for (int ct = 0; ct < 8; ++ct)
            #pragma unroll
            for (int r = 0; r < 4; ++r) {
                int grow = i0 + w * 32 + rt * 16 + lq * 4 + r;
                if (grow < M)
                    out[(size_t)grow * 128 + ct * 16 + lm] =
                        f2bf(fmaxf(acc[rt][ct][r] + bv[ct], 0.f));
            }
}

// ============================ fused edge MLP (bf16 MFMA both stages) ============
#define HSTR 136   // Hs/W2s row stride (pad breaks mod-32 bank aliasing)

__global__ __launch_bounds__(256) void k_mlp(
    const ushort* __restrict__ x16, const int* __restrict__ qs, const int* __restrict__ qd,
    const ushort* __restrict__ W1T, const float* __restrict__ b1,
    const ushort* __restrict__ W2T, const float* __restrict__ b2,
    float* __restrict__ out, int Eq) {
    __shared__ union {
        struct { ushort As[4096]; ushort Bs[4096]; } s1;        // 16 KB
        struct { ushort Hs[128 * HSTR]; ushort W2s[16 * HSTR]; } s2; // ~39 KB
    } sm;
    __shared__ int Ns[256];   // [0..127]=qs, [128..255]=qd
    int tid = threadIdx.x;
    int l = tid & 63, w = tid >> 6;
    int lm = l & 15, lq = l >> 4;
    int e0 = blockIdx.x * 128;
    {
        int r = tid & 127;
        int e = e0 + r; if (e >= Eq) e = Eq - 1;
        Ns[tid] = (tid < 128) ? qs[e] : qd[e];
    }
    __syncthreads();

    int c0 = w * 64 + l, c1 = c0 + 256;
    int rA0 = c0 >> 2, sA0 = (c0 & 3) * 8;
    int rA1 = c1 >> 2, sA1 = (c1 & 3) * 8;
    ushort* As = sm.s1.As;
    ushort* Bs = sm.s1.Bs;

    floatx4 acc[2][8];
    #pragma unroll
    for (int rt = 0; rt < 2; rt++)
        #pragma unroll
        for (int ct = 0; ct < 8; ct++) acc[rt][ct] = (floatx4){0.f, 0.f, 0.f, 0.f};

    for (int kt = 0; kt < 8; ++kt) {
        int kb = (kt & 3) * 32;
        const int* Nbase = (kt < 4) ? Ns : (Ns + 128);
        int n0 = Nbase[rA0], n1 = Nbase[rA1];
        async16(x16 + (size_t)n0 * 128 + kb + sA0, As + w * 512);
        async16(x16 + (size_t)n1 * 128 + kb + sA1, As + 2048 + w * 512);
        async16(W1T + rA0 * 256 + kt * 32 + sA0, Bs + w * 512);
        async16(W1T + rA1 * 256 + kt * 32 + sA1, Bs + 2048 + w * 512);
        __syncthreads();
        bf16x8 a0 = *(const bf16x8*)(As + (w * 32 + lm) * 32 + lq * 8);
        bf16x8 a1 = *(const bf16x8*)(As + (w * 32 + 16 + lm) * 32 + lq * 8);
        #pragma unroll
        for (int ct = 0; ct < 8; ++ct) {
            bf16x8 b = *(const bf16x8*)(Bs + (ct * 16 + lm) * 32 + lq * 8);
            acc[0][ct] = __builtin_amdgcn_mfma_f32_16x16x32_bf16(a0, b, acc[0][ct], 0, 0, 0);
            acc[1][ct] = __builtin_amdgcn_mfma_f32_16x16x32_bf16(a1, b, acc[1][ct], 0, 0, 0);
        }
        __syncthreads();
    }

    // stage-1 epilogue: h = relu(acc + b1) -> Hs (bf16), stage W2 -> W2s
    float b1v[8];
    #pragma unroll
    for (int ct = 0; ct < 8; ++ct) b1v[ct] = b1[ct * 16 + lm];
    #pragma unroll
    for (int rt = 0; rt < 2; ++rt)
        #pragma unroll
        for (int ct = 0; ct < 8; ++ct)
            #pragma unroll
            for (int r = 0; r < 4; ++r) {
                int row = w * 32 + rt * 16 + lq * 4 + r;
                int col = ct * 16 + lm;
                sm.s2.Hs[row * HSTR + col] = f2bf(fmaxf(acc[rt][ct][r] + b1v[ct], 0.f));
            }
    {
        int n = tid >> 4, kc = (tid & 15) * 8;
        #pragma unroll
        for (int j = 0; j < 8; ++j)
            sm.s2.W2s[n * HSTR + kc + j] = W2T[n * 128 + kc + j];
    }
    __syncthreads();

    // stage 2: logits = h @ W2 + b2 (MFMA, N=16 with cols 8..15 zero)
    floatx4 acc2[2];
    acc2[0] = (floatx4){0.f, 0.f, 0.f, 0.f};
    acc2[1] = (floatx4){0.f, 0.f, 0.f, 0.f};
    #pragma unroll
    for (int ks = 0; ks < 4; ++ks) {
        bf16x8 bw = *(const bf16x8*)(sm.s2.W2s + lm * HSTR + ks * 32 + lq * 8);
        bf16x8 h0 = *(const bf16x8*)(sm.s2.Hs + (w * 32 + lm) * HSTR + ks * 32 + lq * 8);
        bf16x8 h1 = *(const bf16x8*)(sm.s2.Hs + (w * 32 + 16 + lm) * HSTR + ks * 32 + lq * 8);
        acc2[0] = __builtin_amdgcn_mfma_f32_16x16x32_bf16(h0, bw, acc2[0], 0, 0, 0);
        acc2[1] = __builtin_amdgcn_mfma_f32_16x16x32_bf16(h1, bw, acc2[1], 0, 0, 0);
    }
    if (lm < 8) {
        float bb = b2[lm];
        #pragma unroll
        for (int rt = 0; rt < 2; ++rt)
            #pragma unroll
            for (int r = 0; r < 4; ++r) {
                int eg = e0 + w * 32 + rt * 16 + lq * 4 + r;
                if (eg < Eq) out[(size_t)eg * 8 + lm] = acc2[rt][r] + bb;
            }
    }
}

// ============================ launch ============================

extern "C" void kernel_launch(void* const* d_in, const int* in_sizes, int n_in,
                              void* d_out, int out_size, void* d_ws, size_t ws_size,
                              hipStream_t stream) {
    const float* node_emb = (const float*)d_in[0];
    const float* Wl0 = (const float*)d_in[1];
    const float* bl0 = (const float*)d_in[2];
    const float* Wr0 = (const float*)d_in[3];
    const float* Wl1 = (const float*)d_in[4];
    const float* bl1 = (const float*)d_in[5];
    const float* Wr1 = (const float*)d_in[6];
    const float* W1  = (const float*)d_in[7];
    const float* b1  = (const float*)d_in[8];
    const float* W2  = (const float*)d_in[9];
    const float* b2  = (const float*)d_in[10];
    const int* eidx  = (const int*)d_in[11];
    const int* eq    = (const int*)d_in[12];

    int N  = in_sizes[0] / HID;
    int E  = in_sizes[11] / 2;
    int Eq = in_sizes[12] / 2;
    const int* srcp = eidx;
    const int* dstp = eidx + E;
    const int* qs = eq;
    const int* qd = eq + Eq;
    float* outp = (float*)d_out;

    char* ws = (char*)d_ws;
    size_t off = 0;
    auto take = [&](size_t bytes) -> char* {
        char* p = ws + off;
        off += (bytes + 255) & ~(size_t)255;
        return p;
    };
    int* deg       = (int*)take((size_t)N * 4);
    int* fillc     = (int*)take((size_t)N * 4);
    int* rowptr    = (int*)take((size_t)(N + 1) * 4);
    int* partials  = (int*)take(512);
    int* csr       = (int*)take((size_t)E * 4);
    ushort* x0_16  = (ushort*)take((size_t)N * HID * 2);
    ushort* mean16 = (ushort*)take((size_t)N * HID * 2);
    ushort* xa16   = (ushort*)take((size_t)N * HID * 2);
    ushort* xb16   = (ushort*)take((size_t)N * HID * 2);
    ushort* WlrT0  = (ushort*)take(32768 * 2);
    ushort* WlrT1  = (ushort*)take(32768 * 2);
    ushort* W1T    = (ushort*)take(32768 * 2);
    ushort* W2T    = (ushort*)take(2048 * 2);

    hipMemsetAsync(deg, 0, (size_t)N * 4, stream);
    hipMemsetAsync(fillc, 0, (size_t)N * 4, stream);

    const int TB = 256;
    int ebl = (E + TB - 1) / TB;
    k_count<<<ebl, TB, 0, stream>>>(dstp, E, deg);
    int nb = (N + 1023) / 1024;
    k_scan1<<<nb, 256, 0, stream>>>(deg, rowptr, partials, N);
    k_scan2<<<1, 128, 0, stream>>>(partials, nb);
    k_scan3<<<(N + 1 + TB - 1) / TB, TB, 0, stream>>>(rowptr, partials, N, E);
    k_fill<<<ebl, TB, 0, stream>>>(srcp, dstp, E, rowptr, fillc, csr);

    int n4 = N * HID / 4;
    k_cvt<<<(n4 + TB - 1) / TB, TB, 0, stream>>>(node_emb, x0_16, n4);
    k_prepw<<<392, 256, 0, stream>>>(Wl0, Wr0, Wl1, Wr1, W1, W2, WlrT0, WlrT1, W1T, W2T);

    int ab = (N + 3) / 4;
    int mg = (N + 127) / 128;
    k_agg16<<<ab, 256, 0, stream>>>(x0_16, rowptr, csr, mean16, N);
    k_gemm16<<<mg, 256, 0, stream>>>(mean16, x0_16, WlrT0, bl0, xa16, N);
    k_agg16<<<ab, 256, 0, stream>>>(xa16, rowptr, csr, mean16, N);
    k_gemm16<<<mg, 256, 0, stream>>>(mean16, xa16, WlrT1, bl1, xb16, N);

    int eg = (Eq + 127) / 128;
    k_mlp<<<eg, 256, 0, stream>>>(xb16, qs, qd, W1T, b1, W2T, b2, outp, Eq);
}

// Round 3
// 469.971 us; speedup vs baseline: 4.2043x; 1.2455x over previous
//
#include <hip/hip_runtime.h>
#include <hip/hip_bf16.h>
#include <cstdint>
#include <cstddef>

#define HID 128
#define SH 9                 // 512 nodes per bin
#define NODES_PER_BIN 512

typedef __attribute__((ext_vector_type(8))) __bf16 bf16x8;
typedef __attribute__((ext_vector_type(4))) float floatx4;

__device__ __forceinline__ ushort f2bf(float f) {
    uint u = __float_as_uint(f);
    u += 0x7fff + ((u >> 16) & 1);          // round-to-nearest-even
    return (ushort)(u >> 16);
}
__device__ __forceinline__ float bf2f(uint h) { return __uint_as_float(h << 16); }

// async global->LDS, 16B per lane; LDS dest must be wave-uniform base + lane*16
__device__ __forceinline__ void async16(const ushort* g, ushort* l) {
    __builtin_amdgcn_global_load_lds(
        (const __attribute__((address_space(1))) uint*)g,
        (__attribute__((address_space(3))) uint*)l, 16, 0, 0);
}

// ============================ binned CSR build ============================

__global__ void k_hist(const int* __restrict__ dst, int E, int* __restrict__ binc) {
    __shared__ int h[256];
    int t = threadIdx.x;
    h[t] = 0;
    __syncthreads();
    for (int e = blockIdx.x * 256 + t; e < E; e += gridDim.x * 256)
        atomicAdd(&h[dst[e] >> SH], 1);
    __syncthreads();
    if (h[t]) atomicAdd(&binc[t], h[t]);
}

__global__ void k_binscan(const int* __restrict__ binc, int* __restrict__ bin_start,
                          int* __restrict__ bin_cursor, int E) {
    __shared__ int s[256];
    int t = threadIdx.x;
    int c = binc[t];
    s[t] = c;
    __syncthreads();
    #pragma unroll
    for (int off = 1; off < 256; off <<= 1) {
        int add = (t >= off) ? s[t - off] : 0;
        __syncthreads();
        s[t] += add;
        __syncthreads();
    }
    int excl = s[t] - c;
    bin_start[t] = excl;
    bin_cursor[t] = excl;
    if (t == 255) bin_start[256] = E;
}

// 2048 edges/block: in-LDS multi-split by bin, then coalesced bin-grouped writes.
// packed word = (d & 511) << 23 | src   (requires src < 2^23)
__global__ __launch_bounds__(256) void k_part(
    const int* __restrict__ src, const int* __restrict__ dst, int E,
    int* __restrict__ bin_cursor, uint* __restrict__ ebuf) {
    __shared__ int h[256];
    __shared__ int sc[256];
    __shared__ int rk[256];
    __shared__ int gb[256];
    __shared__ uint2 ro[2048];   // (d, packed)
    int t = threadIdx.x;
    int base = blockIdx.x * 2048;
    h[t] = 0;
    __syncthreads();
    int dd[8], ss[8];
    bool ok[8];
    #pragma unroll
    for (int k = 0; k < 8; ++k) {
        int e = base + k * 256 + t;
        ok[k] = e < E;
        if (ok[k]) {
            dd[k] = dst[e];
            ss[k] = src[e];
            atomicAdd(&h[dd[k] >> SH], 1);
        }
    }
    __syncthreads();
    sc[t] = h[t];
    __syncthreads();
    #pragma unroll
    for (int off = 1; off < 256; off <<= 1) {
        int add = (t >= off) ? sc[t - off] : 0;
        __syncthreads();
        sc[t] += add;
        __syncthreads();
    }
    rk[t] = sc[t] - h[t];           // exclusive
    {
        int c = h[t];
        if (c > 0) gb[t] = atomicAdd(&bin_cursor[t], c);
    }
    __syncthreads();
    #pragma unroll
    for (int k = 0; k < 8; ++k) {
        if (ok[k]) {
            int bin = dd[k] >> SH;
            int r = atomicAdd(&rk[bin], 1);
            ro[r] = make_uint2((uint)dd[k],
                               ((uint)(dd[k] & (NODES_PER_BIN - 1)) << 23) | (uint)ss[k]);
        }
    }
    __syncthreads();
    int nv = sc[255];
    for (int i = t; i < nv; i += 256) {
        uint2 pr = ro[i];
        int bin = (int)(pr.x >> SH);
        int excl = sc[bin] - h[bin];
        ebuf[gb[bin] + (i - excl)] = pr.y;
    }
}

// one block per bin: exact CSR for 512 nodes via LDS count+scan
__global__ __launch_bounds__(256) void k_csr(
    const uint* __restrict__ ebuf, const int* __restrict__ bin_start,
    int* __restrict__ rowptr, int* __restrict__ csr, int N, int E, int NB) {
    __shared__ int cnt[512];
    __shared__ int p[256];
    __shared__ int excl[512];
    int t = threadIdx.x;
    int b = blockIdx.x;
    int d0 = b << SH;
    int ebase = bin_start[b], eend = bin_start[b + 1];
    cnt[t] = 0; cnt[t + 256] = 0;
    __syncthreads();
    for (int e = ebase + t; e < eend; e += 256)
        atomicAdd(&cnt[ebuf[e] >> 23], 1);
    __syncthreads();
    p[t] = cnt[2 * t] + cnt[2 * t + 1];
    __syncthreads();
    #pragma unroll
    for (int off = 1; off < 256; off <<= 1) {
        int add = (t >= off) ? p[t - off] : 0;
        __syncthreads();
        p[t] += add;
        __syncthreads();
    }
    int e0 = (t == 0) ? 0 : p[t - 1];
    excl[2 * t] = e0;
    excl[2 * t + 1] = e0 + cnt[2 * t];
    __syncthreads();
    #pragma unroll
    for (int i = t; i < 512; i += 256) {
        int node = d0 + i;
        if (node < N) rowptr[node] = ebase + excl[i];
    }
    if (b == NB - 1 && t == 0) rowptr[N] = E;
    __syncthreads();
    for (int e = ebase + t; e < eend; e += 256) {
        uint w = ebuf[e];
        int r = atomicAdd(&excl[w >> 23], 1);
        csr[ebase + r] = (int)(w & 0x7FFFFFu);
    }
}

// ============================ prep: fp32 -> bf16, weight transposes ============

__global__ void k_cvt(const float* __restrict__ in, ushort* __restrict__ out, int n4) {
    int i = blockIdx.x * blockDim.x + threadIdx.x;
    if (i < n4) {
        float4 v = ((const float4*)in)[i];
        ushort4 o;
        o.x = f2bf(v.x); o.y = f2bf(v.y); o.z = f2bf(v.z); o.w = f2bf(v.w);
        ((ushort4*)out)[i] = o;
    }
}

__global__ void k_prepw(const float* __restrict__ Wl0, const float* __restrict__ Wr0,
                        const float* __restrict__ Wl1, const float* __restrict__ Wr1,
                        const float* __restrict__ W1,  const float* __restrict__ W2,
                        ushort* __restrict__ WlrT0, ushort* __restrict__ WlrT1,
                        ushort* __restrict__ W1T,   ushort* __restrict__ W2T) {
    int idx = blockIdx.x * 256 + threadIdx.x;
    if (idx < 32768) {
        int n = idx >> 8, k = idx & 255;
        float v = (k < 128) ? Wl0[k * 128 + n] : Wr0[(k - 128) * 128 + n];
        WlrT0[n * 256 + k] = f2bf(v);
    } else if (idx < 65536) {
        int t = idx - 32768; int n = t >> 8, k = t & 255;
        float v = (k < 128) ? Wl1[k * 128 + n] : Wr1[(k - 128) * 128 + n];
        WlrT1[n * 256 + k] = f2bf(v);
    } else if (idx < 98304) {
        int t = idx - 65536; int n = t >> 8, k = t & 255;
        W1T[n * 256 + k] = f2bf(W1[k * 128 + n]);
    } else if (idx < 100352) {
        int t = idx - 98304; int n = t >> 7, k = t & 127;
        W2T[n * 128 + k] = (n < 8) ? f2bf(W2[k * 8 + n]) : (ushort)0;
    }
}

// ============================ mean aggregation (bf16 in/out) ============================
// one wave per node; half-wave per row (uint2 = 4 channels per lane)
__global__ __launch_bounds__(256) void k_agg16(const ushort* __restrict__ x,
                                               const int* __restrict__ rowptr,
                                               const int* __restrict__ csr,
                                               ushort* __restrict__ mean, int N) {
    int node = blockIdx.x * 4 + (threadIdx.x >> 6);
    if (node >= N) return;
    int l = threadIdx.x & 63;
    int lh = l & 31, hi = l >> 5;
    int b = rowptr[node], e = rowptr[node + 1];
    const uint2* xv = (const uint2*)x;
    float a0 = 0.f, a1 = 0.f, a2 = 0.f, a3 = 0.f;
    for (int j = b; j < e; j += 4) {
        int r0 = j + hi, r1 = j + 2 + hi;
        if (r0 < e) {
            uint2 v = xv[(size_t)csr[r0] * 32 + lh];
            a0 += bf2f(v.x & 0xffffu); a1 += bf2f(v.x >> 16);
            a2 += bf2f(v.y & 0xffffu); a3 += bf2f(v.y >> 16);
        }
        if (r1 < e) {
            uint2 v = xv[(size_t)csr[r1] * 32 + lh];
            a0 += bf2f(v.x & 0xffffu); a1 += bf2f(v.x >> 16);
            a2 += bf2f(v.y & 0xffffu); a3 += bf2f(v.y >> 16);
        }
    }
    a0 += __shfl_xor(a0, 32);
    a1 += __shfl_xor(a1, 32);
    a2 += __shfl_xor(a2, 32);
    a3 += __shfl_xor(a3, 32);
    if (hi == 0) {
        float inv = 1.f / fmaxf((float)(e - b), 1.f);
        uint2 o;
        o.x = (uint)f2bf(a0 * inv) | ((uint)f2bf(a1 * inv) << 16);
        o.y = (uint)f2bf(a2 * inv) | ((uint)f2bf(a3 * inv) << 16);
        ((uint2*)mean)[(size_t)node * 32 + lh] = o;
    }
}

// ============================ layer GEMM (bf16 MFMA) ============================
__global__ __launch_bounds__(256) void k_gemm16(
    const ushort* __restrict__ Alo, const ushort* __restrict__ Ahi,
    const ushort* __restrict__ WT, const float* __restrict__ bias,
    ushort* __restrict__ out, int M) {
    __shared__ ushort As[4096];   // [128 rows][32 k]
    __shared__ ushort Bs[4096];   // [128 n][32 k]
    int tid = threadIdx.x;
    int l = tid & 63, w = tid >> 6;
    int i0 = blockIdx.x * 128;
    int c0 = w * 64 + l, c1 = c0 + 256;
    int rA0 = c0 >> 2, sA0 = (c0 & 3) * 8;
    int rA1 = c1 >> 2, sA1 = (c1 & 3) * 8;
    int g0 = i0 + rA0; if (g0 >= M) g0 = M - 1;
    int g1 = i0 + rA1; if (g1 >= M) g1 = M - 1;
    int lm = l & 15, lq = l >> 4;

    floatx4 acc[2][8];
    #pragma unroll
    for (int rt = 0; rt < 2; rt++)
        #pragma unroll
        for (int ct = 0; ct < 8; ct++) acc[rt][ct] = (floatx4){0.f, 0.f, 0.f, 0.f};

    for (int kt = 0; kt < 8; ++kt) {
        const ushort* Asrc = (kt < 4) ? Alo : Ahi;
        int kb = (kt & 3) * 32;
        async16(Asrc + (size_t)g0 * 128 + kb + sA0, As + w * 512);
        async16(Asrc + (size_t)g1 * 128 + kb + sA1, As + 2048 + w * 512);
        async16(WT + rA0 * 256 + kt * 32 + sA0, Bs + w * 512);
        async16(WT + rA1 * 256 + kt * 32 + sA1, Bs + 2048 + w * 512);
        __syncthreads();
        bf16x8 a0 = *(const bf16x8*)(As + (w * 32 + lm) * 32 + lq * 8);
        bf16x8 a1 = *(const bf16x8*)(As + (w * 32 + 16 + lm) * 32 + lq * 8);
        #pragma unroll
        for (int ct = 0; ct < 8; ++ct) {
            bf16x8 b = *(const bf16x8*)(Bs + (ct * 16 + lm) * 32 + lq * 8);
            acc[0][ct] = __builtin_amdgcn_mfma_f32_16x16x32_bf16(a0, b, acc[0][ct], 0, 0, 0);
            acc[1][ct] = __builtin_amdgcn_mfma_f32_16x16x32_bf16(a1, b, acc[1][ct], 0, 0, 0);
        }
        __syncthreads();
    }

    float bv[8];
    #pragma unroll
    for (int ct = 0; ct < 8; ++ct) bv[ct] = bias[ct * 16 + lm];
    #pragma unroll
    for (int rt = 0; rt < 2; ++rt)
        #pragma unroll
        for (int ct = 0; ct < 8; ++ct)
            #pragma unroll
            for (int r = 0; r < 4; ++r) {
                int grow = i0 + w * 32 + rt * 16 + lq * 4 + r;
                if (grow < M)
                    out[(size_t)grow * 128 + ct * 16 + lm] =
                        f2bf(fmaxf(acc[rt][ct][r] + bv[ct], 0.f));
            }
}

// ============================ fused edge MLP (bf16 MFMA both stages) ============
#define HSTR 136

__global__ __launch_bounds__(256) void k_mlp(
    const ushort* __restrict__ x16, const int* __restrict__ qs, const int* __restrict__ qd,
    const ushort* __restrict__ W1T, const float* __restrict__ b1,
    const ushort* __restrict__ W2T, const float* __restrict__ b2,
    float* __restrict__ out, int Eq) {
    __shared__ union {
        struct { ushort As[4096]; ushort Bs[4096]; } s1;
        struct { ushort Hs[128 * HSTR]; ushort W2s[16 * HSTR]; } s2;
    } sm;
    __shared__ int Ns[256];
    int tid = threadIdx.x;
    int l = tid & 63, w = tid >> 6;
    int lm = l & 15, lq = l >> 4;
    int e0 = blockIdx.x * 128;
    {
        int r = tid & 127;
        int e = e0 + r; if (e >= Eq) e = Eq - 1;
        Ns[tid] = (tid < 128) ? qs[e] : qd[e];
    }
    __syncthreads();

    int c0 = w * 64 + l, c1 = c0 + 256;
    int rA0 = c0 >> 2, sA0 = (c0 & 3) * 8;
    int rA1 = c1 >> 2, sA1 = (c1 & 3) * 8;
    ushort* As = sm.s1.As;
    ushort* Bs = sm.s1.Bs;

    floatx4 acc[2][8];
    #pragma unroll
    for (int rt = 0; rt < 2; rt++)
        #pragma unroll
        for (int ct = 0; ct < 8; ct++) acc[rt][ct] = (floatx4){0.f, 0.f, 0.f, 0.f};

    for (int kt = 0; kt < 8; ++kt) {
        int kb = (kt & 3) * 32;
        const int* Nbase = (kt < 4) ? Ns : (Ns + 128);
        int n0 = Nbase[rA0], n1 = Nbase[rA1];
        async16(x16 + (size_t)n0 * 128 + kb + sA0, As + w * 512);
        async16(x16 + (size_t)n1 * 128 + kb + sA1, As + 2048 + w * 512);
        async16(W1T + rA0 * 256 + kt * 32 + sA0, Bs + w * 512);
        async16(W1T + rA1 * 256 + kt * 32 + sA1, Bs + 2048 + w * 512);
        __syncthreads();
        bf16x8 a0 = *(const bf16x8*)(As + (w * 32 + lm) * 32 + lq * 8);
        bf16x8 a1 = *(const bf16x8*)(As + (w * 32 + 16 + lm) * 32 + lq * 8);
        #pragma unroll
        for (int ct = 0; ct < 8; ++ct) {
            bf16x8 b = *(const bf16x8*)(Bs + (ct * 16 + lm) * 32 + lq * 8);
            acc[0][ct] = __builtin_amdgcn_mfma_f32_16x16x32_bf16(a0, b, acc[0][ct], 0, 0, 0);
            acc[1][ct] = __builtin_amdgcn_mfma_f32_16x16x32_bf16(a1, b, acc[1][ct], 0, 0, 0);
        }
        __syncthreads();
    }

    float b1v[8];
    #pragma unroll
    for (int ct = 0; ct < 8; ++ct) b1v[ct] = b1[ct * 16 + lm];
    #pragma unroll
    for (int rt = 0; rt < 2; ++rt)
        #pragma unroll
        for (int ct = 0; ct < 8; ++ct)
            #pragma unroll
            for (int r = 0; r < 4; ++r) {
                int row = w * 32 + rt * 16 + lq * 4 + r;
                int col = ct * 16 + lm;
                sm.s2.Hs[row * HSTR + col] = f2bf(fmaxf(acc[rt][ct][r] + b1v[ct], 0.f));
            }
    {
        int n = tid >> 4, kc = (tid & 15) * 8;
        #pragma unroll
        for (int j = 0; j < 8; ++j)
            sm.s2.W2s[n * HSTR + kc + j] = W2T[n * 128 + kc + j];
    }
    __syncthreads();

    floatx4 acc2[2];
    acc2[0] = (floatx4){0.f, 0.f, 0.f, 0.f};
    acc2[1] = (floatx4){0.f, 0.f, 0.f, 0.f};
    #pragma unroll
    for (int ks = 0; ks < 4; ++ks) {
        bf16x8 bw = *(const bf16x8*)(sm.s2.W2s + lm * HSTR + ks * 32 + lq * 8);
        bf16x8 h0 = *(const bf16x8*)(sm.s2.Hs + (w * 32 + lm) * HSTR + ks * 32 + lq * 8);
        bf16x8 h1 = *(const bf16x8*)(sm.s2.Hs + (w * 32 + 16 + lm) * HSTR + ks * 32 + lq * 8);
        acc2[0] = __builtin_amdgcn_mfma_f32_16x16x32_bf16(h0, bw, acc2[0], 0, 0, 0);
        acc2[1] = __builtin_amdgcn_mfma_f32_16x16x32_bf16(h1, bw, acc2[1], 0, 0, 0);
    }
    if (lm < 8) {
        float bb = b2[lm];
        #pragma unroll
        for (int rt = 0; rt < 2; ++rt)
            #pragma unroll
            for (int r = 0; r < 4; ++r) {
                int eg = e0 + w * 32 + rt * 16 + lq * 4 + r;
                if (eg < Eq) out[(size_t)eg * 8 + lm] = acc2[rt][r] + bb;
            }
    }
}

// ============================ launch ============================

extern "C" void kernel_launch(void* const* d_in, const int* in_sizes, int n_in,
                              void* d_out, int out_size, void* d_ws, size_t ws_size,
                              hipStream_t stream) {
    const float* node_emb = (const float*)d_in[0];
    const float* Wl0 = (const float*)d_in[1];
    const float* bl0 = (const float*)d_in[2];
    const float* Wr0 = (const float*)d_in[3];
    const float* Wl1 = (const float*)d_in[4];
    const float* bl1 = (const float*)d_in[5];
    const float* Wr1 = (const float*)d_in[6];
    const float* W1  = (const float*)d_in[7];
    const float* b1  = (const float*)d_in[8];
    const float* W2  = (const float*)d_in[9];
    const float* b2  = (const float*)d_in[10];
    const int* eidx  = (const int*)d_in[11];
    const int* eq    = (const int*)d_in[12];

    int N  = in_sizes[0] / HID;
    int E  = in_sizes[11] / 2;
    int Eq = in_sizes[12] / 2;
    const int* srcp = eidx;
    const int* dstp = eidx + E;
    const int* qs = eq;
    const int* qd = eq + Eq;
    float* outp = (float*)d_out;
    int NB = (N + NODES_PER_BIN - 1) >> SH;   // <= 256 (N <= 131072)

    char* ws = (char*)d_ws;
    size_t off = 0;
    auto take = [&](size_t bytes) -> char* {
        char* p = ws + off;
        off += (bytes + 255) & ~(size_t)255;
        return p;
    };
    int* binc       = (int*)take(256 * 4);
    int* bin_start  = (int*)take(257 * 4);
    int* bin_cursor = (int*)take(256 * 4);
    int* rowptr     = (int*)take((size_t)(N + 1) * 4);
    int* csr        = (int*)take((size_t)E * 4);
    // mean16 (25.6MB) aliases ebuf (6.4MB): ebuf dead before first k_agg16 write
    char* meanreg   = take((size_t)N * HID * 2);
    uint* ebuf      = (uint*)meanreg;
    ushort* mean16  = (ushort*)meanreg;
    ushort* x0_16   = (ushort*)take((size_t)N * HID * 2);   // also xb16 (x0 dead after gemm1)
    ushort* xa16    = (ushort*)take((size_t)N * HID * 2);
    ushort* xb16    = x0_16;
    ushort* WlrT0   = (ushort*)take(32768 * 2);
    ushort* WlrT1   = (ushort*)take(32768 * 2);
    ushort* W1T     = (ushort*)take(32768 * 2);
    ushort* W2T     = (ushort*)take(2048 * 2);

    hipMemsetAsync(binc, 0, 256 * 4, stream);

    k_hist<<<256, 256, 0, stream>>>(dstp, E, binc);
    k_binscan<<<1, 256, 0, stream>>>(binc, bin_start, bin_cursor, E);
    int pb = (E + 2047) / 2048;
    k_part<<<pb, 256, 0, stream>>>(srcp, dstp, E, bin_cursor, ebuf);
    k_csr<<<NB, 256, 0, stream>>>(ebuf, bin_start, rowptr, csr, N, E, NB);

    int n4 = N * HID / 4;
    const int TB = 256;
    k_cvt<<<(n4 + TB - 1) / TB, TB, 0, stream>>>(node_emb, x0_16, n4);
    k_prepw<<<392, 256, 0, stream>>>(Wl0, Wr0, Wl1, Wr1, W1, W2, WlrT0, WlrT1, W1T, W2T);

    int ab = (N + 3) / 4;
    int mg = (N + 127) / 128;
    k_agg16<<<ab, 256, 0, stream>>>(x0_16, rowptr, csr, mean16, N);
    k_gemm16<<<mg, 256, 0, stream>>>(mean16, x0_16, WlrT0, bl0, xa16, N);
    k_agg16<<<ab, 256, 0, stream>>>(xa16, rowptr, csr, mean16, N);
    k_gemm16<<<mg, 256, 0, stream>>>(mean16, xa16, WlrT1, bl1, xb16, N);

    int eg = (Eq + 127) / 128;
    k_mlp<<<eg, 256, 0, stream>>>(xb16, qs, qd, W1T, b1, W2T, b2, outp, Eq);
}